// Round 20
// baseline (32.200 us; speedup 1.0000x reference)
//
#include <hip/hip_runtime.h>
#include <hip/hip_fp16.h>

// CapsuleLinear, B=32, I=512, L=64, O=128, J=64, 3 routing iterations.
// Algebraic fusion (no priors): out = W_o @ xc, wn = (G_o @ xc)/||W_o xc||,
// G_o = W_o^T W_o (fp16 lane-major Gq, 1 MB in d_ws).
// r19 = r18 (32.88 us) minus the xT LDS round-trip: each lane's phase-B
// B-fragments are exactly the 4 uint4 it gathered in setup (same qh/nt/g/o15
// indices on write and read), so they live in named registers bt0..bt3.
// amdgpu_num_vgpr(128) (r16/r18-proven at this shape) protects the alloc:
// persistent = af* 16 + bt* 16 + ga* 8 = 40 regs, zero occupancy cost at
// 1 block/CU. Saves 4 b128 LDS reads/lane/pass + setup writes, -64 KB LDS.
// Structure otherwise r14/r18: OPB=16, NT=1024, grid=256 (1 block/CU);
// A-frags hoisted to 4 named half8; dedicated-xcpart-in-dead-xs; G
// double-buffered; scale-invariant softmax (denominator on last pass only).

#define CB 32
#define CI 512
#define CL 64
#define CO 128
#define OPB 16
#define NT 1024

typedef _Float16 half8 __attribute__((ext_vector_type(8)));
typedef float f32x4 __attribute__((ext_vector_type(4)));

static __device__ __forceinline__ _Float16 half_sel(uint v, int sh) {
  union { unsigned short s; _Float16 h; } c;
  c.s = (unsigned short)(v >> sh);
  return c.h;
}

// Gq layout (16B units): unit u = (o*8 + k)*64 + l1 holds pairs p=4k+q for
// ROW l1 (symmetric == column l1): (G[o][l1][8k+2q], G[o][l1][8k+2q+1]).
__global__ __launch_bounds__(256) void caps_gram(const float* __restrict__ wg,
                                                 __half2* __restrict__ Gq) {
  const int o = blockIdx.x;
  const int h = blockIdx.y;        // l1-half: rows h*32 .. h*32+31
  const int t = threadIdx.x;
  __shared__ float wl[64 * 65];    // W[o] padded (+1 col)
#pragma unroll
  for (int k = 0; k < 16; ++k) {
    int f = t + 256 * k;
    int j = f >> 6, l = f & 63;
    wl[j * 65 + l] = wg[(o << 12) + f];
  }
  __syncthreads();
  const int l1 = h * 32 + (t >> 3);
  const int kq = t & 7;
  const int l2b = kq << 3;
  float acc[8];
#pragma unroll
  for (int m = 0; m < 8; ++m) acc[m] = 0.f;
#pragma unroll 4
  for (int j = 0; j < 64; ++j) {
    float wa = wl[j * 65 + l1];
#pragma unroll
    for (int m = 0; m < 8; ++m) acc[m] += wa * wl[j * 65 + l2b + m];
  }
  union { __half2 h2[4]; uint4 u; } pk;
#pragma unroll
  for (int q = 0; q < 4; ++q)
    pk.h2[q] = __floats2half2_rn(acc[2 * q], acc[2 * q + 1]);
  reinterpret_cast<uint4*>(Gq)[(o << 9) + (kq << 6) + l1] = pk.u;
}

__global__ __launch_bounds__(NT)
__attribute__((amdgpu_num_vgpr(128)))
void caps_main(const float* __restrict__ xg,
               const float* __restrict__ wg,
               const __half2* __restrict__ Gq,
               float* __restrict__ outg) {
  const int b = blockIdx.y;
  const int obase = blockIdx.x * OPB;
  const int t = threadIdx.x;
  const int w = t >> 6;          // wave 0..15, owns capsule o = obase + w
  const int lane = t & 63;
  const int g = lane >> 4;
  const int o15 = lane & 15;

  __shared__ __align__(16) _Float16 xs[CI * CL];       // 65536 B (setup only)
  __shared__ __align__(16) _Float16 coefT[OPB * CI];   // 16384 B (dedicated)
  __shared__ __align__(16) _Float16 wn16[OPB * CL];    // 2048 B (swizzled)
  __shared__ __align__(16) float xc_s[OPB * CL];       // 4096 B
  __shared__ float se_part[OPB * OPB];                 // 1024 B (pass 3 only)
  float* const xcpart = reinterpret_cast<float*>(xs);  // 16 KB in dead xs
  char* const xs_b = reinterpret_cast<char*>(xs);
  char* const cf_b = reinterpret_cast<char*>(coefT);
  char* const wn_b = reinterpret_cast<char*>(wn16);
  // total 89088 B -> 1 block/CU, grid 256 = one full-chip round

  const int qh = w >> 2, nt = w & 3;  // phase-B: i-quarter, l-subtile
  const int lcol = nt * 16 + o15;     // this lane's l index in phase B

  // G row pointer (16B units, coalesced across lanes)
  const uint4* Gp = reinterpret_cast<const uint4*>(Gq) +
                    ((obase + w) << 9) + lane;
  uint4 ga0, ga1;  // G double-buffer half (<=8 regs across barriers)

  // ---- stage x[b] -> fp16 subtiled LDS; coalesced float4 global reads ----
  {
    const float4* xg4 = reinterpret_cast<const float4*>(xg + b * (CI * CL));
#pragma unroll
    for (int k = 0; k < 4; ++k) {
      int f = t + NT * k;        // 8-half unit id: row i, l-unit lu
      int i = f >> 3, lu = f & 7;
      float4 a = xg4[2 * f];
      float4 c = xg4[2 * f + 1];
      union { _Float16 h[8]; uint4 u; } cv;
      cv.h[0] = (_Float16)a.x; cv.h[1] = (_Float16)a.y;
      cv.h[2] = (_Float16)a.z; cv.h[3] = (_Float16)a.w;
      cv.h[4] = (_Float16)c.x; cv.h[5] = (_Float16)c.y;
      cv.h[6] = (_Float16)c.z; cv.h[7] = (_Float16)c.w;
      int off = ((i >> 4) * 4 + (lu >> 1)) * 512 + (i & 15) * 32 + (lu & 1) * 16;
      *reinterpret_cast<uint4*>(xs_b + off) = cv.u;
    }
  }
  __syncthreads();

  // ---- setup: gather B-frags into bt0..bt3; hoist A-frags; xbar; G ----
  // btK.h[j] = x[(qh*16 + K*4 + g)*8 + j][lcol]  (kept in registers; the
  // r14/r18 xT write+read used identical indices -> pure round-trip)
  float xbs = 0.f;
  half8 af00, af01, af10, af11;  // phase-A A-frags, pass-invariant (16 VGPRs)
  uint4 bt0, bt1, bt2, bt3;      // phase-B B-frags, pass-invariant (16 VGPRs)
  {
    const uint* xrd32 = reinterpret_cast<const uint*>(
                            xs_b + nt * 512 + ((o15 & 8) << 1)) +
                        ((o15 & 7) >> 1);
    const int sh = (o15 & 1) << 4;
#define GATHW(K, BT)                                                        \
  {                                                                         \
    int P = qh * 16 + (K)*4 + g;                                            \
    const uint* xk = xrd32 + (P >> 1) * 512 + (P & 1) * 64;                 \
    uint d0 = xk[0], d1 = xk[8], d2 = xk[16], d3 = xk[24];                  \
    uint d4 = xk[32], d5 = xk[40], d6 = xk[48], d7 = xk[56];                \
    union { _Float16 h[8]; uint4 u; } fv;                                   \
    fv.h[0] = half_sel(d0, sh); fv.h[1] = half_sel(d1, sh);                 \
    fv.h[2] = half_sel(d2, sh); fv.h[3] = half_sel(d3, sh);                 \
    fv.h[4] = half_sel(d4, sh); fv.h[5] = half_sel(d5, sh);                 \
    fv.h[6] = half_sel(d6, sh); fv.h[7] = half_sel(d7, sh);                 \
    xbs += (float)fv.h[0] + (float)fv.h[1] + (float)fv.h[2] +               \
           (float)fv.h[3] + (float)fv.h[4] + (float)fv.h[5] +               \
           (float)fv.h[6] + (float)fv.h[7];                                 \
    BT = fv.u;                                                              \
  }
    GATHW(0, bt0) GATHW(1, bt1) GATHW(2, bt2) GATHW(3, bt3)
#undef GATHW
    // A-frags: wave w's i-subtiles st = 2w, 2w+1 (same addresses every pass)
    const int abase = (g >> 1) * 512 + o15 * 32 + ((g & 1) << 4);
    af00 = *reinterpret_cast<const half8*>(xs_b + (2 * w) * 2048 + abase);
    af01 = *reinterpret_cast<const half8*>(xs_b + (2 * w) * 2048 + 1024 + abase);
    af10 = *reinterpret_cast<const half8*>(xs_b + (2 * w + 1) * 2048 + abase);
    af11 = *reinterpret_cast<const half8*>(xs_b + (2 * w + 1) * 2048 + 1024 + abase);
    xbs += __shfl_xor(xbs, 16, 64);
    xbs += __shfl_xor(xbs, 32, 64);
    ga0 = Gp[0]; ga1 = Gp[64];  // pass-0 G first pair
  }
  __syncthreads();  // ALL xs reads complete before xcpart overlays it
  if (lane < 16) xcpart[qh * 1024 + nt * 16 + lane] = xbs;  // xbar partials

  for (int pass = 0; pass < 4; ++pass) {
    if (pass > 0) {
      // ---- phase A: logits via MFMA (A-frags from regs); exp -> coefT ----
      half8 bw0 = *reinterpret_cast<const half8*>(
          wn_b + o15 * 128 + ((g ^ (o15 & 7)) << 4));
      half8 bw1 = *reinterpret_cast<const half8*>(
          wn_b + o15 * 128 + (((4 + g) ^ (o15 & 7)) << 4));
      float sacc = 0.f;
#define PHASEA(TI, AF0, AF1)                                                \
  {                                                                         \
    const int st = 2 * w + (TI);                                            \
    f32x4 d = {0.f, 0.f, 0.f, 0.f};                                         \
    d = __builtin_amdgcn_mfma_f32_16x16x32_f16(AF0, bw0, d, 0, 0, 0);       \
    d = __builtin_amdgcn_mfma_f32_16x16x32_f16(AF1, bw1, d, 0, 0, 0);       \
    float e0 = __expf(d[0]), e1 = __expf(d[1]);                             \
    float e2 = __expf(d[2]), e3 = __expf(d[3]);                             \
    sacc += (e0 + e1) + (e2 + e3);                                          \
    int p = st * 2 + (g >> 1);                                              \
    union { _Float16 h[4]; uint2 u; } pk;                                   \
    pk.h[0] = (_Float16)e0; pk.h[1] = (_Float16)e1;                         \
    pk.h[2] = (_Float16)e2; pk.h[3] = (_Float16)e3;                         \
    *reinterpret_cast<uint2*>(cf_b + o15 * 1024 + ((p ^ o15) << 4) +        \
                              ((g & 1) << 3)) = pk.u;                       \
  }
      PHASEA(0, af00, af01)
      PHASEA(1, af10, af11)
#undef PHASEA
      if (pass == 3) {  // softmax denominator only needed on the final pass
        sacc += __shfl_xor(sacc, 16, 64);
        sacc += __shfl_xor(sacc, 32, 64);
        if (lane < 16) se_part[w * 16 + lane] = sacc;  // [i-wave][o]
      }
      __syncthreads();

      // ---- phase B: xc partials, full 16-row MFMA (A b128, B regs) ----
      f32x4 d = {0.f, 0.f, 0.f, 0.f};
#define MFMAK(K, BT)                                                        \
  {                                                                         \
    int p = qh * 16 + (K)*4 + g;                                            \
    half8 a = *reinterpret_cast<const half8*>(cf_b + o15 * 1024 +           \
                                              ((p ^ o15) << 4));            \
    d = __builtin_amdgcn_mfma_f32_16x16x32_f16(                             \
        a, *reinterpret_cast<const half8*>(&BT), d, 0, 0, 0);               \
  }
      MFMAK(0, bt0) MFMAK(1, bt1) MFMAK(2, bt2) MFMAK(3, bt3)
#undef MFMAK
      if (pass < 3) { ga0 = Gp[0]; ga1 = Gp[64]; }  // G pair in flight
#pragma unroll
      for (int r = 0; r < 4; ++r)  // dedicated xcpart: no barrier needed
        xcpart[qh * 1024 + (g * 4 + r) * 64 + lcol] = d[r];
    }
    __syncthreads();

    // ---- finalize: xc (unnormalized until pass 3); wn = G xc/||W xc|| ----
    {
      float sxc;
      if (pass == 0) {
        sxc = xcpart[lane] + xcpart[1024 + lane] + xcpart[2048 + lane] +
              xcpart[3072 + lane];
      } else {
        sxc = xcpart[w * 64 + lane] + xcpart[1024 + w * 64 + lane] +
              xcpart[2048 + w * 64 + lane] + xcpart[3072 + w * 64 + lane];
      }
      float xcv;
      if (pass == 3) {  // apply softmax denominator once at the end
        float sp = se_part[(lane & 15) * 16 + w];
        sp += __shfl_xor(sp, 1, 64);
        sp += __shfl_xor(sp, 2, 64);
        sp += __shfl_xor(sp, 4, 64);
        sp += __shfl_xor(sp, 8, 64);
        xcv = sxc / sp;
      } else {
        xcv = sxc;  // scale cancels inside wn
      }
      xc_s[(w << 6) + lane] = xcv;
      if (pass < 3) {
        const float4* xc4 = reinterpret_cast<const float4*>(&xc_s[w << 6]);
        float u0 = 0.f, u1 = 0.f, u2 = 0.f, u3 = 0.f;
#define GDOT(V, K)                                                          \
  {                                                                         \
    float4 xa = xc4[2 * (K)], xb = xc4[2 * (K) + 1];                        \
    float2 h0 = __half22float2(*reinterpret_cast<const __half2*>(&V.x));    \
    float2 h1 = __half22float2(*reinterpret_cast<const __half2*>(&V.y));    \
    float2 h2 = __half22float2(*reinterpret_cast<const __half2*>(&V.z));    \
    float2 h3 = __half22float2(*reinterpret_cast<const __half2*>(&V.w));    \
    u0 += h0.x * xa.x; u1 += h0.y * xa.y;                                   \
    u2 += h1.x * xa.z; u3 += h1.y * xa.w;                                   \
    u0 += h2.x * xb.x; u1 += h2.y * xb.y;                                   \
    u2 += h3.x * xb.z; u3 += h3.y * xb.w;                                   \
  }
        // double-buffered G: <=16 G regs live, each load hidden under GDOTs
        uint4 gb0 = Gp[128], gb1 = Gp[192];
        GDOT(ga0, 0) GDOT(ga1, 1)
        ga0 = Gp[256]; ga1 = Gp[320];
        GDOT(gb0, 2) GDOT(gb1, 3)
        gb0 = Gp[384]; gb1 = Gp[448];
        GDOT(ga0, 4) GDOT(ga1, 5)
        GDOT(gb0, 6) GDOT(gb1, 7)
#undef GDOT
        float uv = (u0 + u1) + (u2 + u3);
        float sq = uv * xcv;
#pragma unroll
        for (int m = 32; m; m >>= 1) sq += __shfl_xor(sq, m, 64);
        float wnv = uv / fmaxf(sqrtf(fmaxf(sq, 0.f)), 1e-12f);
        union { _Float16 hf; unsigned short us; } wc;
        wc.hf = (_Float16)wnv;
        *reinterpret_cast<unsigned short*>(
            wn_b + w * 128 + (((lane >> 3) ^ (w & 7)) << 4) +
            ((lane & 7) << 1)) = wc.us;
      }
    }
    __syncthreads();
  }

  // ---- epilogue: out[b, obase+w, j=lane] = sum_l W[o][j][l] * xc[o][l] ----
  {
    const float* Wp = wg + ((((obase + w) << 6) + lane) << 6);
    float a0 = 0.f, a1 = 0.f, a2 = 0.f, a3 = 0.f;
#pragma unroll
    for (int k = 0; k < 16; ++k) {
      float4 wv = *reinterpret_cast<const float4*>(&Wp[k << 2]);
      float4 xv = *reinterpret_cast<const float4*>(&xc_s[(w << 6) + (k << 2)]);
      a0 += wv.x * xv.x; a1 += wv.y * xv.y;
      a2 += wv.z * xv.z; a3 += wv.w * xv.w;
    }
    outg[((b << 7) + obase + w) * 64 + lane] = (a0 + a1) + (a2 + a3);
  }
}

extern "C" void kernel_launch(void* const* d_in, const int* in_sizes, int n_in,
                              void* d_out, int out_size, void* d_ws, size_t ws_size,
                              hipStream_t stream) {
  const float* x = (const float*)d_in[0];     // (32, 512, 64) fp32
  const float* wgt = (const float*)d_in[1];   // (128, 64, 64) fp32
  float* out = (float*)d_out;                 // (32, 128, 64) fp32
  __half2* Gq = (__half2*)d_ws;               // 128*8*64 x 16B = 1 MB

  caps_gram<<<dim3(CO, 2), dim3(256), 0, stream>>>(wgt, Gq);
  caps_main<<<dim3(CO / OPB, CB), dim3(NT), 0, stream>>>(x, wgt, Gq, out);
}

// Round 21
// 32.175 us; speedup vs baseline: 1.0008x; 1.0008x over previous
//
#include <hip/hip_runtime.h>
#include <hip/hip_fp16.h>

// CapsuleLinear, B=32, I=512, L=64, O=128, J=64, 3 routing iterations.
// Algebraic fusion (no priors): out = W_o @ xc, wn = (G_o @ xc)/||W_o xc||,
// G_o = W_o^T W_o (fp16 lane-major Gq, 1 MB in d_ws).
// r21 = r19/r20 (best: 32.2 us) + W epilogue prefetch: by pass-3 phase B the
// af*/bt*/ga* registers (40 VGPRs) are dead, so W[o][j=lane][:] (16 uint4)
// is prefetched there, removing the exposed L2 latency from the tail.
// Structure (all measured-optimal across r1-r20): OPB=16, NT=1024, grid=256
// (1 block/CU); A-frags hoisted to 4 named half8; B-frags in 4 named uint4
// (no xT round-trip); dedicated-xcpart-in-dead-xs (3 barriers/pass =
// structural minimum for the all-to-all dataflow); G double-buffered;
// scale-invariant softmax (denominator on last pass only);
// amdgpu_num_vgpr(128) pins the register tier (r16/r18-proven).

#define CB 32
#define CI 512
#define CL 64
#define CO 128
#define OPB 16
#define NT 1024

typedef _Float16 half8 __attribute__((ext_vector_type(8)));
typedef float f32x4 __attribute__((ext_vector_type(4)));

static __device__ __forceinline__ _Float16 half_sel(uint v, int sh) {
  union { unsigned short s; _Float16 h; } c;
  c.s = (unsigned short)(v >> sh);
  return c.h;
}

// Gq layout (16B units): unit u = (o*8 + k)*64 + l1 holds pairs p=4k+q for
// ROW l1 (symmetric == column l1): (G[o][l1][8k+2q], G[o][l1][8k+2q+1]).
__global__ __launch_bounds__(256) void caps_gram(const float* __restrict__ wg,
                                                 __half2* __restrict__ Gq) {
  const int o = blockIdx.x;
  const int h = blockIdx.y;        // l1-half: rows h*32 .. h*32+31
  const int t = threadIdx.x;
  __shared__ float wl[64 * 65];    // W[o] padded (+1 col)
#pragma unroll
  for (int k = 0; k < 16; ++k) {
    int f = t + 256 * k;
    int j = f >> 6, l = f & 63;
    wl[j * 65 + l] = wg[(o << 12) + f];
  }
  __syncthreads();
  const int l1 = h * 32 + (t >> 3);
  const int kq = t & 7;
  const int l2b = kq << 3;
  float acc[8];
#pragma unroll
  for (int m = 0; m < 8; ++m) acc[m] = 0.f;
#pragma unroll 4
  for (int j = 0; j < 64; ++j) {
    float wa = wl[j * 65 + l1];
#pragma unroll
    for (int m = 0; m < 8; ++m) acc[m] += wa * wl[j * 65 + l2b + m];
  }
  union { __half2 h2[4]; uint4 u; } pk;
#pragma unroll
  for (int q = 0; q < 4; ++q)
    pk.h2[q] = __floats2half2_rn(acc[2 * q], acc[2 * q + 1]);
  reinterpret_cast<uint4*>(Gq)[(o << 9) + (kq << 6) + l1] = pk.u;
}

__global__ __launch_bounds__(NT)
__attribute__((amdgpu_num_vgpr(128)))
void caps_main(const float* __restrict__ xg,
               const float* __restrict__ wg,
               const __half2* __restrict__ Gq,
               float* __restrict__ outg) {
  const int b = blockIdx.y;
  const int obase = blockIdx.x * OPB;
  const int t = threadIdx.x;
  const int w = t >> 6;          // wave 0..15, owns capsule o = obase + w
  const int lane = t & 63;
  const int g = lane >> 4;
  const int o15 = lane & 15;

  __shared__ __align__(16) _Float16 xs[CI * CL];       // 65536 B (setup only)
  __shared__ __align__(16) _Float16 coefT[OPB * CI];   // 16384 B (dedicated)
  __shared__ __align__(16) _Float16 wn16[OPB * CL];    // 2048 B (swizzled)
  __shared__ __align__(16) float xc_s[OPB * CL];       // 4096 B
  __shared__ float se_part[OPB * OPB];                 // 1024 B (pass 3 only)
  float* const xcpart = reinterpret_cast<float*>(xs);  // 16 KB in dead xs
  char* const xs_b = reinterpret_cast<char*>(xs);
  char* const cf_b = reinterpret_cast<char*>(coefT);
  char* const wn_b = reinterpret_cast<char*>(wn16);
  // total 89088 B -> 1 block/CU, grid 256 = one full-chip round

  const int qh = w >> 2, nt = w & 3;  // phase-B: i-quarter, l-subtile
  const int lcol = nt * 16 + o15;     // this lane's l index in phase B

  // G row pointer (16B units, coalesced across lanes)
  const uint4* Gp = reinterpret_cast<const uint4*>(Gq) +
                    ((obase + w) << 9) + lane;
  uint4 ga0, ga1;  // G double-buffer half (<=8 regs across barriers)

  // W row pointer for the epilogue (prefetched during pass 3)
  const uint4* Wq = reinterpret_cast<const uint4*>(
      wg + ((((obase + w) << 6) + lane) << 6));
  uint4 wp0, wp1, wp2, wp3, wp4, wp5, wp6, wp7;
  uint4 wp8, wp9, wp10, wp11, wp12, wp13, wp14, wp15;

  // ---- stage x[b] -> fp16 subtiled LDS; coalesced float4 global reads ----
  {
    const float4* xg4 = reinterpret_cast<const float4*>(xg + b * (CI * CL));
#pragma unroll
    for (int k = 0; k < 4; ++k) {
      int f = t + NT * k;        // 8-half unit id: row i, l-unit lu
      int i = f >> 3, lu = f & 7;
      float4 a = xg4[2 * f];
      float4 c = xg4[2 * f + 1];
      union { _Float16 h[8]; uint4 u; } cv;
      cv.h[0] = (_Float16)a.x; cv.h[1] = (_Float16)a.y;
      cv.h[2] = (_Float16)a.z; cv.h[3] = (_Float16)a.w;
      cv.h[4] = (_Float16)c.x; cv.h[5] = (_Float16)c.y;
      cv.h[6] = (_Float16)c.z; cv.h[7] = (_Float16)c.w;
      int off = ((i >> 4) * 4 + (lu >> 1)) * 512 + (i & 15) * 32 + (lu & 1) * 16;
      *reinterpret_cast<uint4*>(xs_b + off) = cv.u;
    }
  }
  __syncthreads();

  // ---- setup: gather B-frags into bt0..bt3; hoist A-frags; xbar; G ----
  // btK.h[j] = x[(qh*16 + K*4 + g)*8 + j][lcol]
  float xbs = 0.f;
  half8 af00, af01, af10, af11;  // phase-A A-frags, pass-invariant (16 VGPRs)
  uint4 bt0, bt1, bt2, bt3;      // phase-B B-frags, pass-invariant (16 VGPRs)
  {
    const uint* xrd32 = reinterpret_cast<const uint*>(
                            xs_b + nt * 512 + ((o15 & 8) << 1)) +
                        ((o15 & 7) >> 1);
    const int sh = (o15 & 1) << 4;
#define GATHW(K, BT)                                                        \
  {                                                                         \
    int P = qh * 16 + (K)*4 + g;                                            \
    const uint* xk = xrd32 + (P >> 1) * 512 + (P & 1) * 64;                 \
    uint d0 = xk[0], d1 = xk[8], d2 = xk[16], d3 = xk[24];                  \
    uint d4 = xk[32], d5 = xk[40], d6 = xk[48], d7 = xk[56];                \
    union { _Float16 h[8]; uint4 u; } fv;                                   \
    fv.h[0] = half_sel(d0, sh); fv.h[1] = half_sel(d1, sh);                 \
    fv.h[2] = half_sel(d2, sh); fv.h[3] = half_sel(d3, sh);                 \
    fv.h[4] = half_sel(d4, sh); fv.h[5] = half_sel(d5, sh);                 \
    fv.h[6] = half_sel(d6, sh); fv.h[7] = half_sel(d7, sh);                 \
    xbs += (float)fv.h[0] + (float)fv.h[1] + (float)fv.h[2] +               \
           (float)fv.h[3] + (float)fv.h[4] + (float)fv.h[5] +               \
           (float)fv.h[6] + (float)fv.h[7];                                 \
    BT = fv.u;                                                              \
  }
    GATHW(0, bt0) GATHW(1, bt1) GATHW(2, bt2) GATHW(3, bt3)
#undef GATHW
    // A-frags: wave w's i-subtiles st = 2w, 2w+1 (same addresses every pass)
    const int abase = (g >> 1) * 512 + o15 * 32 + ((g & 1) << 4);
    af00 = *reinterpret_cast<const half8*>(xs_b + (2 * w) * 2048 + abase);
    af01 = *reinterpret_cast<const half8*>(xs_b + (2 * w) * 2048 + 1024 + abase);
    af10 = *reinterpret_cast<const half8*>(xs_b + (2 * w + 1) * 2048 + abase);
    af11 = *reinterpret_cast<const half8*>(xs_b + (2 * w + 1) * 2048 + 1024 + abase);
    xbs += __shfl_xor(xbs, 16, 64);
    xbs += __shfl_xor(xbs, 32, 64);
    ga0 = Gp[0]; ga1 = Gp[64];  // pass-0 G first pair
  }
  __syncthreads();  // ALL xs reads complete before xcpart overlays it
  if (lane < 16) xcpart[qh * 1024 + nt * 16 + lane] = xbs;  // xbar partials

  for (int pass = 0; pass < 4; ++pass) {
    if (pass > 0) {
      // ---- phase A: logits via MFMA (A-frags from regs); exp -> coefT ----
      half8 bw0 = *reinterpret_cast<const half8*>(
          wn_b + o15 * 128 + ((g ^ (o15 & 7)) << 4));
      half8 bw1 = *reinterpret_cast<const half8*>(
          wn_b + o15 * 128 + (((4 + g) ^ (o15 & 7)) << 4));
      float sacc = 0.f;
#define PHASEA(TI, AF0, AF1)                                                \
  {                                                                         \
    const int st = 2 * w + (TI);                                            \
    f32x4 d = {0.f, 0.f, 0.f, 0.f};                                         \
    d = __builtin_amdgcn_mfma_f32_16x16x32_f16(AF0, bw0, d, 0, 0, 0);       \
    d = __builtin_amdgcn_mfma_f32_16x16x32_f16(AF1, bw1, d, 0, 0, 0);       \
    float e0 = __expf(d[0]), e1 = __expf(d[1]);                             \
    float e2 = __expf(d[2]), e3 = __expf(d[3]);                             \
    sacc += (e0 + e1) + (e2 + e3);                                          \
    int p = st * 2 + (g >> 1);                                              \
    union { _Float16 h[4]; uint2 u; } pk;                                   \
    pk.h[0] = (_Float16)e0; pk.h[1] = (_Float16)e1;                         \
    pk.h[2] = (_Float16)e2; pk.h[3] = (_Float16)e3;                         \
    *reinterpret_cast<uint2*>(cf_b + o15 * 1024 + ((p ^ o15) << 4) +        \
                              ((g & 1) << 3)) = pk.u;                       \
  }
      PHASEA(0, af00, af01)
      PHASEA(1, af10, af11)
#undef PHASEA
      if (pass == 3) {  // softmax denominator only needed on the final pass
        sacc += __shfl_xor(sacc, 16, 64);
        sacc += __shfl_xor(sacc, 32, 64);
        if (lane < 16) se_part[w * 16 + lane] = sacc;  // [i-wave][o]
      }
      __syncthreads();

      // ---- phase B: xc partials, full 16-row MFMA (A b128, B regs) ----
      f32x4 d = {0.f, 0.f, 0.f, 0.f};
#define MFMAK(K, BT)                                                        \
  {                                                                         \
    int p = qh * 16 + (K)*4 + g;                                            \
    half8 a = *reinterpret_cast<const half8*>(cf_b + o15 * 1024 +           \
                                              ((p ^ o15) << 4));            \
    d = __builtin_amdgcn_mfma_f32_16x16x32_f16(                             \
        a, *reinterpret_cast<const half8*>(&BT), d, 0, 0, 0);               \
  }
      MFMAK(0, bt0) MFMAK(1, bt1) MFMAK(2, bt2) MFMAK(3, bt3)
#undef MFMAK
      if (pass < 3) {
        ga0 = Gp[0]; ga1 = Gp[64];  // G pair in flight
      } else {
        // af*/bt*/ga* all dead now: prefetch W row for the epilogue
        wp0 = Wq[0];   wp1 = Wq[1];   wp2 = Wq[2];   wp3 = Wq[3];
        wp4 = Wq[4];   wp5 = Wq[5];   wp6 = Wq[6];   wp7 = Wq[7];
        wp8 = Wq[8];   wp9 = Wq[9];   wp10 = Wq[10]; wp11 = Wq[11];
        wp12 = Wq[12]; wp13 = Wq[13]; wp14 = Wq[14]; wp15 = Wq[15];
      }
#pragma unroll
      for (int r = 0; r < 4; ++r)  // dedicated xcpart: no barrier needed
        xcpart[qh * 1024 + (g * 4 + r) * 64 + lcol] = d[r];
    }
    __syncthreads();

    // ---- finalize: xc (unnormalized until pass 3); wn = G xc/||W xc|| ----
    {
      float sxc;
      if (pass == 0) {
        sxc = xcpart[lane] + xcpart[1024 + lane] + xcpart[2048 + lane] +
              xcpart[3072 + lane];
      } else {
        sxc = xcpart[w * 64 + lane] + xcpart[1024 + w * 64 + lane] +
              xcpart[2048 + w * 64 + lane] + xcpart[3072 + w * 64 + lane];
      }
      float xcv;
      if (pass == 3) {  // apply softmax denominator once at the end
        float sp = se_part[(lane & 15) * 16 + w];
        sp += __shfl_xor(sp, 1, 64);
        sp += __shfl_xor(sp, 2, 64);
        sp += __shfl_xor(sp, 4, 64);
        sp += __shfl_xor(sp, 8, 64);
        xcv = sxc / sp;
      } else {
        xcv = sxc;  // scale cancels inside wn
      }
      xc_s[(w << 6) + lane] = xcv;
      if (pass < 3) {
        const float4* xc4 = reinterpret_cast<const float4*>(&xc_s[w << 6]);
        float u0 = 0.f, u1 = 0.f, u2 = 0.f, u3 = 0.f;
#define GDOT(V, K)                                                          \
  {                                                                         \
    float4 xa = xc4[2 * (K)], xb = xc4[2 * (K) + 1];                        \
    float2 h0 = __half22float2(*reinterpret_cast<const __half2*>(&V.x));    \
    float2 h1 = __half22float2(*reinterpret_cast<const __half2*>(&V.y));    \
    float2 h2 = __half22float2(*reinterpret_cast<const __half2*>(&V.z));    \
    float2 h3 = __half22float2(*reinterpret_cast<const __half2*>(&V.w));    \
    u0 += h0.x * xa.x; u1 += h0.y * xa.y;                                   \
    u2 += h1.x * xa.z; u3 += h1.y * xa.w;                                   \
    u0 += h2.x * xb.x; u1 += h2.y * xb.y;                                   \
    u2 += h3.x * xb.z; u3 += h3.y * xb.w;                                   \
  }
        // double-buffered G: <=16 G regs live, each load hidden under GDOTs
        uint4 gb0 = Gp[128], gb1 = Gp[192];
        GDOT(ga0, 0) GDOT(ga1, 1)
        ga0 = Gp[256]; ga1 = Gp[320];
        GDOT(gb0, 2) GDOT(gb1, 3)
        gb0 = Gp[384]; gb1 = Gp[448];
        GDOT(ga0, 4) GDOT(ga1, 5)
        GDOT(gb0, 6) GDOT(gb1, 7)
#undef GDOT
        float uv = (u0 + u1) + (u2 + u3);
        float sq = uv * xcv;
#pragma unroll
        for (int m = 32; m; m >>= 1) sq += __shfl_xor(sq, m, 64);
        float wnv = uv / fmaxf(sqrtf(fmaxf(sq, 0.f)), 1e-12f);
        union { _Float16 hf; unsigned short us; } wc;
        wc.hf = (_Float16)wnv;
        *reinterpret_cast<unsigned short*>(
            wn_b + w * 128 + (((lane >> 3) ^ (w & 7)) << 4) +
            ((lane & 7) << 1)) = wc.us;
      }
    }
    __syncthreads();
  }

  // ---- epilogue: out[b, obase+w, j=lane] = W[o][j][:] . xc (W in regs) ----
  {
    const float4* xc4 = reinterpret_cast<const float4*>(&xc_s[w << 6]);
    float a0 = 0.f, a1 = 0.f, a2 = 0.f, a3 = 0.f;
#define WDOT(V, K)                                                          \
  {                                                                         \
    float4 wv = *reinterpret_cast<const float4*>(&V);                       \
    float4 xv = xc4[K];                                                     \
    a0 += wv.x * xv.x; a1 += wv.y * xv.y;                                   \
    a2 += wv.z * xv.z; a3 += wv.w * xv.w;                                   \
  }
    WDOT(wp0, 0)   WDOT(wp1, 1)   WDOT(wp2, 2)   WDOT(wp3, 3)
    WDOT(wp4, 4)   WDOT(wp5, 5)   WDOT(wp6, 6)   WDOT(wp7, 7)
    WDOT(wp8, 8)   WDOT(wp9, 9)   WDOT(wp10, 10) WDOT(wp11, 11)
    WDOT(wp12, 12) WDOT(wp13, 13) WDOT(wp14, 14) WDOT(wp15, 15)
#undef WDOT
    outg[((b << 7) + obase + w) * 64 + lane] = (a0 + a1) + (a2 + a3);
  }
}

extern "C" void kernel_launch(void* const* d_in, const int* in_sizes, int n_in,
                              void* d_out, int out_size, void* d_ws, size_t ws_size,
                              hipStream_t stream) {
  const float* x = (const float*)d_in[0];     // (32, 512, 64) fp32
  const float* wgt = (const float*)d_in[1];   // (128, 64, 64) fp32
  float* out = (float*)d_out;                 // (32, 128, 64) fp32
  __half2* Gq = (__half2*)d_ws;               // 128*8*64 x 16B = 1 MB

  caps_gram<<<dim3(CO, 2), dim3(256), 0, stream>>>(wgt, Gq);
  caps_main<<<dim3(CO / OPB, CB), dim3(NT), 0, stream>>>(x, wgt, Gq, out);
}